// Round 13
// baseline (165.248 us; speedup 1.0000x reference)
//
#include <hip/hip_runtime.h>
#include <hip/hip_bf16.h>
#include <math.h>

// GCN 2-layer forward, round-13: r12 structure with two latency fixes:
//   - k_scat1 CH 4096->2048: 1564 blocks (6/CU, ~24 waves/CU) vs 782 (3/CU).
//     r12 counters: scat1 43us @ 690GB/s, VALUBusy 1.6%, occ 20% -> pure
//     latency-bound; traffic floor ~5us. Trade: runs 42->21 edges (~84B),
//     write-amp ~1.25->~1.5x (+1us BW) for 2x latency hiding.
//   - k_agg1 unroll 4->8: 8 independent gather chains in flight per thread.
// Everything else unchanged. Assumes N <= 131072.

#define F_IN 128
#define H1 16
#define C_OUT 2
#define SBS 1024         // nodes per super-bucket
#define LOG_SBS 10
#define NSB_MAX 128
#define SRC_MASK 0x3FFFFF   // 22-bit src
#define CH1 2048         // edges per chunk in scat1
#define SLICE 128        // nodes per place-slice
#define NSLICE (SBS / SLICE)   // 8
#define PCAP 5632        // staged edges per slice (expected ~4096, +24 sigma)

typedef int ix4 __attribute__((ext_vector_type(4)));

__device__ __forceinline__ float bflo(unsigned u) { return __uint_as_float(u << 16); }
__device__ __forceinline__ float bfhi(unsigned u) { return __uint_as_float(u & 0xFFFF0000u); }

// ---- init: per-SB write cursors at region bases; final rp entry ----
__global__ void k_init(int* __restrict__ gcur_sb, int* __restrict__ rp,
                       int NSB, int CAP, int E) {
    int t = threadIdx.x;
    if (t < NSB) gcur_sb[t] = t * CAP;
    if (t == 0) rp[NSB * SBS] = E;
}

// ---- pass 1: chunk-scatter (src | dst_local<<22) into SB regions ----
__global__ __launch_bounds__(256) void k_scat1(
    const int* __restrict__ src0, const int* __restrict__ dst0,
    int* __restrict__ gcur_sb, unsigned* __restrict__ packed1, int E, int NSB) {
    __shared__ int hist[NSB_MAX];
    __shared__ int lcur[NSB_MAX];
    int t = threadIdx.x;
    if (t < NSB) hist[t] = 0;
    __syncthreads();
    int e0 = blockIdx.x * CH1, e1 = min(e0 + CH1, E);
    int n4 = (e1 - e0) >> 2;
    const ix4* d4 = (const ix4*)(dst0 + e0);
    const ix4* s4 = (const ix4*)(src0 + e0);
    for (int i = t; i < n4; i += 256) {
        ix4 d = __builtin_nontemporal_load(&d4[i]);
        atomicAdd(&hist[((unsigned)d.x) >> LOG_SBS], 1);
        atomicAdd(&hist[((unsigned)d.y) >> LOG_SBS], 1);
        atomicAdd(&hist[((unsigned)d.z) >> LOG_SBS], 1);
        atomicAdd(&hist[((unsigned)d.w) >> LOG_SBS], 1);
    }
    for (int e = e0 + n4 * 4 + t; e < e1; e += 256)
        atomicAdd(&hist[((unsigned)dst0[e]) >> LOG_SBS], 1);
    __syncthreads();
    if (t < NSB) {
        int h = hist[t];
        lcur[t] = h ? atomicAdd(&gcur_sb[t], h) : 0;
    }
    __syncthreads();
    for (int i = t; i < n4; i += 256) {
        ix4 d = __builtin_nontemporal_load(&d4[i]);
        ix4 s = __builtin_nontemporal_load(&s4[i]);
        {
            unsigned dd = (unsigned)d.x;
            int pos = atomicAdd(&lcur[dd >> LOG_SBS], 1);
            packed1[pos] = (unsigned)s.x | ((dd & (SBS - 1)) << 22);
        }
        {
            unsigned dd = (unsigned)d.y;
            int pos = atomicAdd(&lcur[dd >> LOG_SBS], 1);
            packed1[pos] = (unsigned)s.y | ((dd & (SBS - 1)) << 22);
        }
        {
            unsigned dd = (unsigned)d.z;
            int pos = atomicAdd(&lcur[dd >> LOG_SBS], 1);
            packed1[pos] = (unsigned)s.z | ((dd & (SBS - 1)) << 22);
        }
        {
            unsigned dd = (unsigned)d.w;
            int pos = atomicAdd(&lcur[dd >> LOG_SBS], 1);
            packed1[pos] = (unsigned)s.w | ((dd & (SBS - 1)) << 22);
        }
    }
    for (int e = e0 + n4 * 4 + t; e < e1; e += 256) {
        unsigned dd = (unsigned)dst0[e];
        int pos = atomicAdd(&lcur[dd >> LOG_SBS], 1);
        packed1[pos] = (unsigned)src0[e] | ((dd & (SBS - 1)) << 22);
    }
}

// ---- pass 2a: per-SB histogram + scan -> rp (ALL nodes of SB), dinv ----
__global__ __launch_bounds__(1024) void k_hist(
    const unsigned* __restrict__ packed1, const int* __restrict__ gcur_sb,
    int* __restrict__ rp, float* __restrict__ dinv, int N, int NSB, int CAP) {
    __shared__ int cnt[SBS];
    __shared__ int s2[SBS];
    __shared__ int sbase[NSB_MAX];
    int b = blockIdx.x, t = threadIdx.x;
    if (t < NSB_MAX) sbase[t] = (t < NSB) ? (gcur_sb[t] - t * CAP) : 0;
    cnt[t] = 0;
    __syncthreads();
    if (t == 0) {
        int run = 0;
        #pragma unroll 4
        for (int i = 0; i < NSB_MAX; ++i) { int c = sbase[i]; sbase[i] = run; run += c; }
    }
    __syncthreads();
    int cntb = gcur_sb[b] - b * CAP;
    int e0 = b * CAP, e1 = e0 + cntb;
    int obase = sbase[b];
    int n4 = cntb >> 2;
    const ix4* p4 = (const ix4*)(packed1 + e0);
    for (int i = t; i < n4; i += 1024) {
        ix4 p = p4[i];
        atomicAdd(&cnt[((unsigned)p.x) >> 22], 1);
        atomicAdd(&cnt[((unsigned)p.y) >> 22], 1);
        atomicAdd(&cnt[((unsigned)p.z) >> 22], 1);
        atomicAdd(&cnt[((unsigned)p.w) >> 22], 1);
    }
    for (int e = e0 + n4 * 4 + t; e < e1; e += 1024)
        atomicAdd(&cnt[packed1[e] >> 22], 1);
    __syncthreads();
    int c = cnt[t];
    s2[t] = c;
    __syncthreads();
    for (int off = 1; off < 1024; off <<= 1) {
        int v = (t >= off) ? s2[t - off] : 0;
        __syncthreads();
        s2[t] += v;
        __syncthreads();
    }
    int ep = s2[t] - c;                 // exclusive prefix within SB
    int node = (b << LOG_SBS) + t;
    rp[node] = obase + ep;              // defined for ALL SB nodes
    if (node < N) dinv[node] = rsqrtf((float)(c + 1));   // +1 self-loop
}

// ---- pass 2b: placement, 8 slice-blocks per SB; LDS-staged sequential out ----
__global__ __launch_bounds__(512) void k_place(
    const unsigned* __restrict__ packed1, const int* __restrict__ gcur_sb,
    const int* __restrict__ rp, int* __restrict__ packed2,
    int NSB, int PADB, int CAP) {
    __shared__ int cur[SLICE];
    __shared__ int lbuf[PCAP];
    int bid = blockIdx.x;
    int s = bid / PADB, b = bid - s * PADB;
    if (b >= NSB) return;
    int t = threadIdx.x;
    int node0 = (b << LOG_SBS) + s * SLICE;
    int g0 = rp[node0];
    if (t < SLICE) cur[t] = rp[node0 + t] - g0;
    int slice_len = rp[node0 + SLICE] - g0;
    __syncthreads();
    int cntb = gcur_sb[b] - b * CAP;
    int e0 = b * CAP, e1 = e0 + cntb;
    int n4 = cntb >> 2;
    const ix4* p4 = (const ix4*)(packed1 + e0);
    for (int i = t; i < n4; i += 512) {
        ix4 p = p4[i];
        {
            unsigned nd = ((unsigned)p.x) >> 22;
            if ((nd >> 7) == (unsigned)s) {
                int pos = atomicAdd(&cur[nd & (SLICE - 1)], 1);
                if (pos < PCAP) lbuf[pos] = p.x & SRC_MASK;
            }
        }
        {
            unsigned nd = ((unsigned)p.y) >> 22;
            if ((nd >> 7) == (unsigned)s) {
                int pos = atomicAdd(&cur[nd & (SLICE - 1)], 1);
                if (pos < PCAP) lbuf[pos] = p.y & SRC_MASK;
            }
        }
        {
            unsigned nd = ((unsigned)p.z) >> 22;
            if ((nd >> 7) == (unsigned)s) {
                int pos = atomicAdd(&cur[nd & (SLICE - 1)], 1);
                if (pos < PCAP) lbuf[pos] = p.z & SRC_MASK;
            }
        }
        {
            unsigned nd = ((unsigned)p.w) >> 22;
            if ((nd >> 7) == (unsigned)s) {
                int pos = atomicAdd(&cur[nd & (SLICE - 1)], 1);
                if (pos < PCAP) lbuf[pos] = p.w & SRC_MASK;
            }
        }
    }
    for (int e = e0 + n4 * 4 + t; e < e1; e += 512) {
        unsigned p = packed1[e];
        unsigned nd = p >> 22;
        if ((nd >> 7) == (unsigned)s) {
            int pos = atomicAdd(&cur[nd & (SLICE - 1)], 1);
            if (pos < PCAP) lbuf[pos] = (int)(p & SRC_MASK);
        }
    }
    __syncthreads();
    int lim = min(slice_len, PCAP);
    for (int i = t; i < lim; i += 512)
        packed2[g0 + i] = lbuf[i];      // sequential full-line writes
}

// ---- layer 1 GEMM: h1b = bf16((x@W1)*dinv) ----
__global__ __launch_bounds__(256) void k_gemm1(
    const float* __restrict__ x, const float* __restrict__ W1,
    const float* __restrict__ dinv, __hip_bfloat16* __restrict__ h1b, int N) {
    __shared__ float w[F_IN * H1];    // 8 KB
    __shared__ float xt[16 * F_IN];   // 8 KB
    int tid = threadIdx.x;
    int node0 = blockIdx.x * 16;

    const float4* W14 = (const float4*)W1;
    float4* w4 = (float4*)w;
    for (int i = tid; i < F_IN * H1 / 4; i += 256) w4[i] = W14[i];

    const float4* x4 = (const float4*)x;
    float4* xt4 = (float4*)xt;
    for (int i = tid; i < 16 * F_IN / 4; i += 256) {
        int r = i >> 5;
        int node = node0 + r;
        xt4[i] = (node < N) ? x4[(size_t)node * 32 + (i & 31)]
                            : make_float4(0.f, 0.f, 0.f, 0.f);
    }
    __syncthreads();

    int nsub = tid >> 4, f = tid & 15;
    int node = node0 + nsub;
    if (node < N) {
        const float* xr = xt + nsub * F_IN;
        float acc = 0.0f;
        #pragma unroll 16
        for (int k = 0; k < F_IN; ++k)
            acc = fmaf(xr[k], w[k * H1 + f], acc);
        h1b[(size_t)node * H1 + f] = __float2bfloat16(acc * dinv[node]);
    }
}

// ---- layer 1 aggregate + layer 2 transform, thread per (node, feature-half) ----
// 8 independent gather chains in flight per thread.
__global__ __launch_bounds__(256) void k_agg1(
    const int* __restrict__ packed2, const int* __restrict__ rp,
    const __hip_bfloat16* __restrict__ h1b, const float* __restrict__ dinv,
    const float* __restrict__ b1, const float* __restrict__ W2,
    float* __restrict__ h2s, int N) {
    int tid = blockIdx.x * 256 + threadIdx.x;
    int n = tid >> 1, q = tid & 1;
    if (n >= N) return;
    const uint4* h4 = (const uint4*)h1b;
    float a[8];
    {   // self-loop init: own pre-scaled row half
        uint4 s = h4[(size_t)n * 2 + q];
        a[0] = bflo(s.x); a[1] = bfhi(s.x); a[2] = bflo(s.y); a[3] = bfhi(s.y);
        a[4] = bflo(s.z); a[5] = bfhi(s.z); a[6] = bflo(s.w); a[7] = bfhi(s.w);
    }
    int e = rp[n], e1 = rp[n + 1];
    for (; e + 8 <= e1; e += 8) {
        int p[8];
        #pragma unroll
        for (int u = 0; u < 8; ++u) p[u] = packed2[e + u];
        uint4 v[8];
        #pragma unroll
        for (int u = 0; u < 8; ++u) v[u] = h4[(size_t)p[u] * 2 + q];
        #pragma unroll
        for (int u = 0; u < 8; ++u) {
            a[0] += bflo(v[u].x); a[1] += bfhi(v[u].x);
            a[2] += bflo(v[u].y); a[3] += bfhi(v[u].y);
            a[4] += bflo(v[u].z); a[5] += bfhi(v[u].z);
            a[6] += bflo(v[u].w); a[7] += bfhi(v[u].w);
        }
    }
    for (; e < e1; ++e) {
        int p = packed2[e];
        uint4 v = h4[(size_t)p * 2 + q];
        a[0] += bflo(v.x); a[1] += bfhi(v.x); a[2] += bflo(v.y); a[3] += bfhi(v.y);
        a[4] += bflo(v.z); a[5] += bfhi(v.z); a[6] += bflo(v.w); a[7] += bfhi(v.w);
    }
    float dv = dinv[n];
    float c0 = 0.f, c1 = 0.f;
    #pragma unroll
    for (int j = 0; j < 8; ++j) {
        int f = q * 8 + j;
        float vv = fmaxf(fmaf(a[j], dv, b1[f]), 0.f);
        c0 = fmaf(vv, W2[f * C_OUT + 0], c0);
        c1 = fmaf(vv, W2[f * C_OUT + 1], c1);
    }
    c0 += __shfl_xor(c0, 1);
    c1 += __shfl_xor(c1, 1);
    if (q == 0)
        ((float2*)h2s)[n] = make_float2(c0 * dv, c1 * dv);
}

// ---- layer 2 aggregate + log_softmax, thread per node ----
__global__ __launch_bounds__(256) void k_agg2(
    const int* __restrict__ packed2, const int* __restrict__ rp,
    const float* __restrict__ h2s, const float* __restrict__ dinv,
    const float* __restrict__ b2, float* __restrict__ out, int N) {
    int n = blockIdx.x * 256 + threadIdx.x;
    if (n >= N) return;
    const float2* h2 = (const float2*)h2s;
    float2 self = h2[n];
    float a0 = self.x, a1 = self.y;
    int e = rp[n], e1 = rp[n + 1];
    for (; e + 8 <= e1; e += 8) {
        int p[8];
        #pragma unroll
        for (int u = 0; u < 8; ++u) p[u] = packed2[e + u];
        float2 v[8];
        #pragma unroll
        for (int u = 0; u < 8; ++u) v[u] = h2[p[u]];
        #pragma unroll
        for (int u = 0; u < 8; ++u) { a0 += v[u].x; a1 += v[u].y; }
    }
    for (; e < e1; ++e) {
        float2 v = h2[packed2[e]];
        a0 += v.x; a1 += v.y;
    }
    float dv = dinv[n];
    a0 = fmaf(a0, dv, b2[0]);
    a1 = fmaf(a1, dv, b2[1]);
    float m = fmaxf(a0, a1);
    float lse = m + logf(expf(a0 - m) + expf(a1 - m));
    ((float2*)out)[n] = make_float2(a0 - lse, a1 - lse);
}

extern "C" void kernel_launch(void* const* d_in, const int* in_sizes, int n_in,
                              void* d_out, int out_size, void* d_ws, size_t ws_size,
                              hipStream_t stream) {
    const float* x  = (const float*)d_in[0];
    const int* ei   = (const int*)d_in[1];
    const float* W1 = (const float*)d_in[2];
    const float* b1 = (const float*)d_in[3];
    const float* W2 = (const float*)d_in[4];
    const float* b2 = (const float*)d_in[5];
    float* out = (float*)d_out;

    const int N = in_sizes[0] / F_IN;     // 100000 (assumed <= 131072)
    const int E = in_sizes[1] / 2;        // 3200000
    const int* src0 = ei;
    const int* dst0 = ei + E;

    const int NSB = (N + SBS - 1) >> LOG_SBS;    // 98
    const int nblk = (E + CH1 - 1) / CH1;        // 1563
    const int PADB = (NSB + 7) & ~7;             // 104 (x8 XCD-stable mapping)
    // per-SB capacity: expected (for a full SB) + 12.5% + 2048, 16-aligned
    int expSB = (int)(((long long)E << LOG_SBS) / N);
    int CAP = (expSB + expSB / 8 + 2048 + 15) & ~15;

    // workspace layout (float units), 16B-aligned chunks
    size_t off = 0;
    float* wsf = (float*)d_ws;
    auto take = [&](size_t nf) { float* p = wsf + off; off += (nf + 3) & ~(size_t)3; return p; };
    float* dinv    = take(N);
    __hip_bfloat16* h1b = (__hip_bfloat16*)take((size_t)N * H1 / 2);
    float* h2s     = take((size_t)N * C_OUT);
    unsigned* packed1 = (unsigned*)take((size_t)NSB * CAP);
    int*   packed2 = (int*)take(E);
    int*   gcur_sb = (int*)take(NSB_MAX);
    int*   rp      = (int*)take((size_t)NSB * SBS + 1);

    k_init<<<1, 256, 0, stream>>>(gcur_sb, rp, NSB, CAP, E);
    k_scat1<<<nblk, 256, 0, stream>>>(src0, dst0, gcur_sb, packed1, E, NSB);
    k_hist<<<NSB, 1024, 0, stream>>>(packed1, gcur_sb, rp, dinv, N, NSB, CAP);
    k_place<<<NSLICE * PADB, 512, 0, stream>>>(packed1, gcur_sb, rp, packed2, NSB, PADB, CAP);
    k_gemm1<<<(N + 15) / 16, 256, 0, stream>>>(x, W1, dinv, h1b, N);
    k_agg1<<<(2 * N + 255) / 256, 256, 0, stream>>>(packed2, rp, h1b, dinv, b1, W2, h2s, N);
    k_agg2<<<(N + 255) / 256, 256, 0, stream>>>(packed2, rp, h2s, dinv, b2, out, N);
}

// Round 14
// 141.929 us; speedup vs baseline: 1.1643x; 1.1643x over previous
//
#include <hip/hip_runtime.h>
#include <hip/hip_bf16.h>
#include <math.h>

// GCN 2-layer forward, round-14: r12 structure, but scat1's global-atomic
// reservation chain (r13 evidence: time scales with nblk -> serialized
// same-address RMW at coherence point) replaced by a deterministic
// count + column-scan prepass: zero global atomics anywhere in the pipeline.
//   k_cnt   (782 blocks): per-chunk SB histogram -> cntm[sb][blk]
//   k_cscan (98 blocks):  per-SB exclusive scan over chunks + tot[sb]
//   k_scat1 (782 blocks): scatter at precomputed offsets (LDS ordering only)
//   k_hist/k_place/k_gemm1/k_agg1/k_agg2 as in r12/r13 (agg unroll-8).
// Assumes N <= 131072.

#define F_IN 128
#define H1 16
#define C_OUT 2
#define SBS 1024         // nodes per super-bucket
#define LOG_SBS 10
#define NSB_MAX 128
#define SRC_MASK 0x3FFFFF   // 22-bit src
#define CH1 4096         // edges per chunk (782 chunks)
#define SLICE 128        // nodes per place-slice
#define NSLICE (SBS / SLICE)   // 8
#define PCAP 5632        // staged edges per slice (expected ~4096, +24 sigma)

typedef int ix4 __attribute__((ext_vector_type(4)));

__device__ __forceinline__ float bflo(unsigned u) { return __uint_as_float(u << 16); }
__device__ __forceinline__ float bfhi(unsigned u) { return __uint_as_float(u & 0xFFFF0000u); }

// ---- pass 0a: per-chunk histogram of super-buckets; cntm layout [NSB][nblk] ----
__global__ __launch_bounds__(256) void k_cnt(
    const int* __restrict__ dst0, int* __restrict__ cntm, int E, int NSB, int nblk) {
    __shared__ int sc[NSB_MAX];
    int t = threadIdx.x;
    if (t < NSB_MAX) sc[t] = 0;
    __syncthreads();
    int e0 = blockIdx.x * CH1, e1 = min(e0 + CH1, E);
    int n4 = (e1 - e0) >> 2;
    const ix4* d4 = (const ix4*)(dst0 + e0);
    for (int i = t; i < n4; i += 256) {
        ix4 d = __builtin_nontemporal_load(&d4[i]);
        atomicAdd(&sc[((unsigned)d.x) >> LOG_SBS], 1);
        atomicAdd(&sc[((unsigned)d.y) >> LOG_SBS], 1);
        atomicAdd(&sc[((unsigned)d.z) >> LOG_SBS], 1);
        atomicAdd(&sc[((unsigned)d.w) >> LOG_SBS], 1);
    }
    for (int e = e0 + n4 * 4 + t; e < e1; e += 256)
        atomicAdd(&sc[((unsigned)dst0[e]) >> LOG_SBS], 1);
    __syncthreads();
    for (int b = t; b < NSB; b += 256)
        cntm[(size_t)b * nblk + blockIdx.x] = sc[b];
}

// ---- pass 0b: per-SB exclusive scan over chunks (block per SB) + totals ----
__global__ __launch_bounds__(1024) void k_cscan(
    int* __restrict__ cntm, int* __restrict__ tot, int* __restrict__ rp,
    int NSB, int nblk, int E) {
    __shared__ int s[1024];
    int b = blockIdx.x, t = threadIdx.x;
    int* row = cntm + (size_t)b * nblk;
    int own = (t < nblk) ? row[t] : 0;
    s[t] = own;
    __syncthreads();
    for (int off = 1; off < 1024; off <<= 1) {
        int v = (t >= off) ? s[t - off] : 0;
        __syncthreads();
        s[t] += v;
        __syncthreads();
    }
    if (t < nblk) row[t] = s[t] - own;      // exclusive prefix
    if (t == 0) tot[b] = s[1023];           // SB total (zero-padded tail)
    if (b == 0 && t == 0) rp[NSB * SBS] = E;
}

// ---- pass 1: scatter (src | dst_local<<22) at precomputed offsets ----
__global__ __launch_bounds__(256) void k_scat1(
    const int* __restrict__ src0, const int* __restrict__ dst0,
    const int* __restrict__ cntm, unsigned* __restrict__ packed1,
    int E, int NSB, int nblk, int CAP) {
    __shared__ int lcur[NSB_MAX];
    int t = threadIdx.x, blk = blockIdx.x;
    for (int b = t; b < NSB; b += 256)
        lcur[b] = b * CAP + cntm[(size_t)b * nblk + blk];
    __syncthreads();
    int e0 = blk * CH1, e1 = min(e0 + CH1, E);
    int n4 = (e1 - e0) >> 2;
    const ix4* d4 = (const ix4*)(dst0 + e0);
    const ix4* s4 = (const ix4*)(src0 + e0);
    for (int i = t; i < n4; i += 256) {
        ix4 d = __builtin_nontemporal_load(&d4[i]);
        ix4 s = __builtin_nontemporal_load(&s4[i]);
        {
            unsigned dd = (unsigned)d.x;
            int pos = atomicAdd(&lcur[dd >> LOG_SBS], 1);
            packed1[pos] = (unsigned)s.x | ((dd & (SBS - 1)) << 22);
        }
        {
            unsigned dd = (unsigned)d.y;
            int pos = atomicAdd(&lcur[dd >> LOG_SBS], 1);
            packed1[pos] = (unsigned)s.y | ((dd & (SBS - 1)) << 22);
        }
        {
            unsigned dd = (unsigned)d.z;
            int pos = atomicAdd(&lcur[dd >> LOG_SBS], 1);
            packed1[pos] = (unsigned)s.z | ((dd & (SBS - 1)) << 22);
        }
        {
            unsigned dd = (unsigned)d.w;
            int pos = atomicAdd(&lcur[dd >> LOG_SBS], 1);
            packed1[pos] = (unsigned)s.w | ((dd & (SBS - 1)) << 22);
        }
    }
    for (int e = e0 + n4 * 4 + t; e < e1; e += 256) {
        unsigned dd = (unsigned)dst0[e];
        int pos = atomicAdd(&lcur[dd >> LOG_SBS], 1);
        packed1[pos] = (unsigned)src0[e] | ((dd & (SBS - 1)) << 22);
    }
}

// ---- pass 2a: per-SB histogram + scan -> rp (ALL nodes of SB), dinv ----
__global__ __launch_bounds__(1024) void k_hist(
    const unsigned* __restrict__ packed1, const int* __restrict__ tot,
    int* __restrict__ rp, float* __restrict__ dinv, int N, int NSB, int CAP) {
    __shared__ int cnt[SBS];
    __shared__ int s2[SBS];
    __shared__ int sbase[NSB_MAX];
    int b = blockIdx.x, t = threadIdx.x;
    if (t < NSB_MAX) sbase[t] = (t < NSB) ? tot[t] : 0;
    cnt[t] = 0;
    __syncthreads();
    if (t == 0) {
        int run = 0;
        #pragma unroll 4
        for (int i = 0; i < NSB_MAX; ++i) { int c = sbase[i]; sbase[i] = run; run += c; }
    }
    __syncthreads();
    int cntb = tot[b];
    int e0 = b * CAP, e1 = e0 + cntb;
    int obase = sbase[b];
    int n4 = cntb >> 2;
    const ix4* p4 = (const ix4*)(packed1 + e0);
    for (int i = t; i < n4; i += 1024) {
        ix4 p = p4[i];
        atomicAdd(&cnt[((unsigned)p.x) >> 22], 1);
        atomicAdd(&cnt[((unsigned)p.y) >> 22], 1);
        atomicAdd(&cnt[((unsigned)p.z) >> 22], 1);
        atomicAdd(&cnt[((unsigned)p.w) >> 22], 1);
    }
    for (int e = e0 + n4 * 4 + t; e < e1; e += 1024)
        atomicAdd(&cnt[packed1[e] >> 22], 1);
    __syncthreads();
    int c = cnt[t];
    s2[t] = c;
    __syncthreads();
    for (int off = 1; off < 1024; off <<= 1) {
        int v = (t >= off) ? s2[t - off] : 0;
        __syncthreads();
        s2[t] += v;
        __syncthreads();
    }
    int ep = s2[t] - c;                 // exclusive prefix within SB
    int node = (b << LOG_SBS) + t;
    rp[node] = obase + ep;              // defined for ALL SB nodes
    if (node < N) dinv[node] = rsqrtf((float)(c + 1));   // +1 self-loop
}

// ---- pass 2b: placement, 8 slice-blocks per SB; LDS-staged sequential out ----
__global__ __launch_bounds__(512) void k_place(
    const unsigned* __restrict__ packed1, const int* __restrict__ tot,
    const int* __restrict__ rp, int* __restrict__ packed2,
    int NSB, int PADB, int CAP) {
    __shared__ int cur[SLICE];
    __shared__ int lbuf[PCAP];
    int bid = blockIdx.x;
    int s = bid / PADB, b = bid - s * PADB;
    if (b >= NSB) return;
    int t = threadIdx.x;
    int node0 = (b << LOG_SBS) + s * SLICE;
    int g0 = rp[node0];
    if (t < SLICE) cur[t] = rp[node0 + t] - g0;
    int slice_len = rp[node0 + SLICE] - g0;
    __syncthreads();
    int cntb = tot[b];
    int e0 = b * CAP, e1 = e0 + cntb;
    int n4 = cntb >> 2;
    const ix4* p4 = (const ix4*)(packed1 + e0);
    for (int i = t; i < n4; i += 512) {
        ix4 p = p4[i];
        {
            unsigned nd = ((unsigned)p.x) >> 22;
            if ((nd >> 7) == (unsigned)s) {
                int pos = atomicAdd(&cur[nd & (SLICE - 1)], 1);
                if (pos < PCAP) lbuf[pos] = p.x & SRC_MASK;
            }
        }
        {
            unsigned nd = ((unsigned)p.y) >> 22;
            if ((nd >> 7) == (unsigned)s) {
                int pos = atomicAdd(&cur[nd & (SLICE - 1)], 1);
                if (pos < PCAP) lbuf[pos] = p.y & SRC_MASK;
            }
        }
        {
            unsigned nd = ((unsigned)p.z) >> 22;
            if ((nd >> 7) == (unsigned)s) {
                int pos = atomicAdd(&cur[nd & (SLICE - 1)], 1);
                if (pos < PCAP) lbuf[pos] = p.z & SRC_MASK;
            }
        }
        {
            unsigned nd = ((unsigned)p.w) >> 22;
            if ((nd >> 7) == (unsigned)s) {
                int pos = atomicAdd(&cur[nd & (SLICE - 1)], 1);
                if (pos < PCAP) lbuf[pos] = p.w & SRC_MASK;
            }
        }
    }
    for (int e = e0 + n4 * 4 + t; e < e1; e += 512) {
        unsigned p = packed1[e];
        unsigned nd = p >> 22;
        if ((nd >> 7) == (unsigned)s) {
            int pos = atomicAdd(&cur[nd & (SLICE - 1)], 1);
            if (pos < PCAP) lbuf[pos] = (int)(p & SRC_MASK);
        }
    }
    __syncthreads();
    int lim = min(slice_len, PCAP);
    for (int i = t; i < lim; i += 512)
        packed2[g0 + i] = lbuf[i];      // sequential full-line writes
}

// ---- layer 1 GEMM: h1b = bf16((x@W1)*dinv) ----
__global__ __launch_bounds__(256) void k_gemm1(
    const float* __restrict__ x, const float* __restrict__ W1,
    const float* __restrict__ dinv, __hip_bfloat16* __restrict__ h1b, int N) {
    __shared__ float w[F_IN * H1];    // 8 KB
    __shared__ float xt[16 * F_IN];   // 8 KB
    int tid = threadIdx.x;
    int node0 = blockIdx.x * 16;

    const float4* W14 = (const float4*)W1;
    float4* w4 = (float4*)w;
    for (int i = tid; i < F_IN * H1 / 4; i += 256) w4[i] = W14[i];

    const float4* x4 = (const float4*)x;
    float4* xt4 = (float4*)xt;
    for (int i = tid; i < 16 * F_IN / 4; i += 256) {
        int r = i >> 5;
        int node = node0 + r;
        xt4[i] = (node < N) ? x4[(size_t)node * 32 + (i & 31)]
                            : make_float4(0.f, 0.f, 0.f, 0.f);
    }
    __syncthreads();

    int nsub = tid >> 4, f = tid & 15;
    int node = node0 + nsub;
    if (node < N) {
        const float* xr = xt + nsub * F_IN;
        float acc = 0.0f;
        #pragma unroll 16
        for (int k = 0; k < F_IN; ++k)
            acc = fmaf(xr[k], w[k * H1 + f], acc);
        h1b[(size_t)node * H1 + f] = __float2bfloat16(acc * dinv[node]);
    }
}

// ---- layer 1 aggregate + layer 2 transform, thread per (node, feature-half) ----
__global__ __launch_bounds__(256) void k_agg1(
    const int* __restrict__ packed2, const int* __restrict__ rp,
    const __hip_bfloat16* __restrict__ h1b, const float* __restrict__ dinv,
    const float* __restrict__ b1, const float* __restrict__ W2,
    float* __restrict__ h2s, int N) {
    int tid = blockIdx.x * 256 + threadIdx.x;
    int n = tid >> 1, q = tid & 1;
    if (n >= N) return;
    const uint4* h4 = (const uint4*)h1b;
    float a[8];
    {   // self-loop init: own pre-scaled row half
        uint4 s = h4[(size_t)n * 2 + q];
        a[0] = bflo(s.x); a[1] = bfhi(s.x); a[2] = bflo(s.y); a[3] = bfhi(s.y);
        a[4] = bflo(s.z); a[5] = bfhi(s.z); a[6] = bflo(s.w); a[7] = bfhi(s.w);
    }
    int e = rp[n], e1 = rp[n + 1];
    for (; e + 8 <= e1; e += 8) {
        int p[8];
        #pragma unroll
        for (int u = 0; u < 8; ++u) p[u] = packed2[e + u];
        uint4 v[8];
        #pragma unroll
        for (int u = 0; u < 8; ++u) v[u] = h4[(size_t)p[u] * 2 + q];
        #pragma unroll
        for (int u = 0; u < 8; ++u) {
            a[0] += bflo(v[u].x); a[1] += bfhi(v[u].x);
            a[2] += bflo(v[u].y); a[3] += bfhi(v[u].y);
            a[4] += bflo(v[u].z); a[5] += bfhi(v[u].z);
            a[6] += bflo(v[u].w); a[7] += bfhi(v[u].w);
        }
    }
    for (; e < e1; ++e) {
        int p = packed2[e];
        uint4 v = h4[(size_t)p * 2 + q];
        a[0] += bflo(v.x); a[1] += bfhi(v.x); a[2] += bflo(v.y); a[3] += bfhi(v.y);
        a[4] += bflo(v.z); a[5] += bfhi(v.z); a[6] += bflo(v.w); a[7] += bfhi(v.w);
    }
    float dv = dinv[n];
    float c0 = 0.f, c1 = 0.f;
    #pragma unroll
    for (int j = 0; j < 8; ++j) {
        int f = q * 8 + j;
        float vv = fmaxf(fmaf(a[j], dv, b1[f]), 0.f);
        c0 = fmaf(vv, W2[f * C_OUT + 0], c0);
        c1 = fmaf(vv, W2[f * C_OUT + 1], c1);
    }
    c0 += __shfl_xor(c0, 1);
    c1 += __shfl_xor(c1, 1);
    if (q == 0)
        ((float2*)h2s)[n] = make_float2(c0 * dv, c1 * dv);
}

// ---- layer 2 aggregate + log_softmax, thread per node ----
__global__ __launch_bounds__(256) void k_agg2(
    const int* __restrict__ packed2, const int* __restrict__ rp,
    const float* __restrict__ h2s, const float* __restrict__ dinv,
    const float* __restrict__ b2, float* __restrict__ out, int N) {
    int n = blockIdx.x * 256 + threadIdx.x;
    if (n >= N) return;
    const float2* h2 = (const float2*)h2s;
    float2 self = h2[n];
    float a0 = self.x, a1 = self.y;
    int e = rp[n], e1 = rp[n + 1];
    for (; e + 8 <= e1; e += 8) {
        int p[8];
        #pragma unroll
        for (int u = 0; u < 8; ++u) p[u] = packed2[e + u];
        float2 v[8];
        #pragma unroll
        for (int u = 0; u < 8; ++u) v[u] = h2[p[u]];
        #pragma unroll
        for (int u = 0; u < 8; ++u) { a0 += v[u].x; a1 += v[u].y; }
    }
    for (; e < e1; ++e) {
        float2 v = h2[packed2[e]];
        a0 += v.x; a1 += v.y;
    }
    float dv = dinv[n];
    a0 = fmaf(a0, dv, b2[0]);
    a1 = fmaf(a1, dv, b2[1]);
    float m = fmaxf(a0, a1);
    float lse = m + logf(expf(a0 - m) + expf(a1 - m));
    ((float2*)out)[n] = make_float2(a0 - lse, a1 - lse);
}

extern "C" void kernel_launch(void* const* d_in, const int* in_sizes, int n_in,
                              void* d_out, int out_size, void* d_ws, size_t ws_size,
                              hipStream_t stream) {
    const float* x  = (const float*)d_in[0];
    const int* ei   = (const int*)d_in[1];
    const float* W1 = (const float*)d_in[2];
    const float* b1 = (const float*)d_in[3];
    const float* W2 = (const float*)d_in[4];
    const float* b2 = (const float*)d_in[5];
    float* out = (float*)d_out;

    const int N = in_sizes[0] / F_IN;     // 100000 (assumed <= 131072)
    const int E = in_sizes[1] / 2;        // 3200000
    const int* src0 = ei;
    const int* dst0 = ei + E;

    const int NSB = (N + SBS - 1) >> LOG_SBS;    // 98
    const int nblk = (E + CH1 - 1) / CH1;        // 782 (must be <= 1024 for cscan)
    const int PADB = (NSB + 7) & ~7;             // 104 (x8 XCD-stable mapping)
    // per-SB capacity: expected (for a full SB) + 12.5% + 2048, 16-aligned
    int expSB = (int)(((long long)E << LOG_SBS) / N);
    int CAP = (expSB + expSB / 8 + 2048 + 15) & ~15;

    // workspace layout (float units), 16B-aligned chunks
    size_t off = 0;
    float* wsf = (float*)d_ws;
    auto take = [&](size_t nf) { float* p = wsf + off; off += (nf + 3) & ~(size_t)3; return p; };
    float* dinv    = take(N);
    __hip_bfloat16* h1b = (__hip_bfloat16*)take((size_t)N * H1 / 2);
    float* h2s     = take((size_t)N * C_OUT);
    unsigned* packed1 = (unsigned*)take((size_t)NSB * CAP);
    int*   packed2 = (int*)take(E);
    int*   cntm    = (int*)take((size_t)NSB * nblk);
    int*   tot     = (int*)take(NSB_MAX);
    int*   rp      = (int*)take((size_t)NSB * SBS + 1);

    k_cnt<<<nblk, 256, 0, stream>>>(dst0, cntm, E, NSB, nblk);
    k_cscan<<<NSB, 1024, 0, stream>>>(cntm, tot, rp, NSB, nblk, E);
    k_scat1<<<nblk, 256, 0, stream>>>(src0, dst0, cntm, packed1, E, NSB, nblk, CAP);
    k_hist<<<NSB, 1024, 0, stream>>>(packed1, tot, rp, dinv, N, NSB, CAP);
    k_place<<<NSLICE * PADB, 512, 0, stream>>>(packed1, tot, rp, packed2, NSB, PADB, CAP);
    k_gemm1<<<(N + 15) / 16, 256, 0, stream>>>(x, W1, dinv, h1b, N);
    k_agg1<<<(2 * N + 255) / 256, 256, 0, stream>>>(packed2, rp, h1b, dinv, b1, W2, h2s, N);
    k_agg2<<<(N + 255) / 256, 256, 0, stream>>>(packed2, rp, h2s, dinv, b2, out, N);
}

// Round 15
// 141.019 us; speedup vs baseline: 1.1718x; 1.0065x over previous
//
#include <hip/hip_runtime.h>
#include <hip/hip_bf16.h>
#include <math.h>

// GCN 2-layer forward, round-15: r14 pipeline (atomic-free count+scan+scatter,
// hist+place to CSR, register-accumulated aggregation) with aggregation
// occupancy doubled: agg kernels were grid-starved (agg1: 782 blocks = 12
// waves/CU; agg2: 391 blocks) and L2-gather-latency-bound.
//   k_agg1: 4 threads/node (8B of the 32B bf16 row each) -> 1563 blocks,
//           24 waves/CU; W2 epilogue via 2x shfl_xor reduce.
//   k_agg2: 2 threads/node (one output channel each) -> 782 blocks.
// Same bytes and cache lines touched; only more waves in flight.
// Assumes N <= 131072.

#define F_IN 128
#define H1 16
#define C_OUT 2
#define SBS 1024         // nodes per super-bucket
#define LOG_SBS 10
#define NSB_MAX 128
#define SRC_MASK 0x3FFFFF   // 22-bit src
#define CH1 4096         // edges per chunk (782 chunks)
#define SLICE 128        // nodes per place-slice
#define NSLICE (SBS / SLICE)   // 8
#define PCAP 5632        // staged edges per slice (expected ~4096, +24 sigma)

typedef int ix4 __attribute__((ext_vector_type(4)));

__device__ __forceinline__ float bflo(unsigned u) { return __uint_as_float(u << 16); }
__device__ __forceinline__ float bfhi(unsigned u) { return __uint_as_float(u & 0xFFFF0000u); }

// ---- pass 0a: per-chunk histogram of super-buckets; cntm layout [NSB][nblk] ----
__global__ __launch_bounds__(256) void k_cnt(
    const int* __restrict__ dst0, int* __restrict__ cntm, int E, int NSB, int nblk) {
    __shared__ int sc[NSB_MAX];
    int t = threadIdx.x;
    if (t < NSB_MAX) sc[t] = 0;
    __syncthreads();
    int e0 = blockIdx.x * CH1, e1 = min(e0 + CH1, E);
    int n4 = (e1 - e0) >> 2;
    const ix4* d4 = (const ix4*)(dst0 + e0);
    for (int i = t; i < n4; i += 256) {
        ix4 d = __builtin_nontemporal_load(&d4[i]);
        atomicAdd(&sc[((unsigned)d.x) >> LOG_SBS], 1);
        atomicAdd(&sc[((unsigned)d.y) >> LOG_SBS], 1);
        atomicAdd(&sc[((unsigned)d.z) >> LOG_SBS], 1);
        atomicAdd(&sc[((unsigned)d.w) >> LOG_SBS], 1);
    }
    for (int e = e0 + n4 * 4 + t; e < e1; e += 256)
        atomicAdd(&sc[((unsigned)dst0[e]) >> LOG_SBS], 1);
    __syncthreads();
    for (int b = t; b < NSB; b += 256)
        cntm[(size_t)b * nblk + blockIdx.x] = sc[b];
}

// ---- pass 0b: per-SB exclusive scan over chunks (block per SB) + totals ----
__global__ __launch_bounds__(1024) void k_cscan(
    int* __restrict__ cntm, int* __restrict__ tot, int* __restrict__ rp,
    int NSB, int nblk, int E) {
    __shared__ int s[1024];
    int b = blockIdx.x, t = threadIdx.x;
    int* row = cntm + (size_t)b * nblk;
    int own = (t < nblk) ? row[t] : 0;
    s[t] = own;
    __syncthreads();
    for (int off = 1; off < 1024; off <<= 1) {
        int v = (t >= off) ? s[t - off] : 0;
        __syncthreads();
        s[t] += v;
        __syncthreads();
    }
    if (t < nblk) row[t] = s[t] - own;      // exclusive prefix
    if (t == 0) tot[b] = s[1023];           // SB total (zero-padded tail)
    if (b == 0 && t == 0) rp[NSB * SBS] = E;
}

// ---- pass 1: scatter (src | dst_local<<22) at precomputed offsets ----
__global__ __launch_bounds__(256) void k_scat1(
    const int* __restrict__ src0, const int* __restrict__ dst0,
    const int* __restrict__ cntm, unsigned* __restrict__ packed1,
    int E, int NSB, int nblk, int CAP) {
    __shared__ int lcur[NSB_MAX];
    int t = threadIdx.x, blk = blockIdx.x;
    for (int b = t; b < NSB; b += 256)
        lcur[b] = b * CAP + cntm[(size_t)b * nblk + blk];
    __syncthreads();
    int e0 = blk * CH1, e1 = min(e0 + CH1, E);
    int n4 = (e1 - e0) >> 2;
    const ix4* d4 = (const ix4*)(dst0 + e0);
    const ix4* s4 = (const ix4*)(src0 + e0);
    for (int i = t; i < n4; i += 256) {
        ix4 d = __builtin_nontemporal_load(&d4[i]);
        ix4 s = __builtin_nontemporal_load(&s4[i]);
        {
            unsigned dd = (unsigned)d.x;
            int pos = atomicAdd(&lcur[dd >> LOG_SBS], 1);
            packed1[pos] = (unsigned)s.x | ((dd & (SBS - 1)) << 22);
        }
        {
            unsigned dd = (unsigned)d.y;
            int pos = atomicAdd(&lcur[dd >> LOG_SBS], 1);
            packed1[pos] = (unsigned)s.y | ((dd & (SBS - 1)) << 22);
        }
        {
            unsigned dd = (unsigned)d.z;
            int pos = atomicAdd(&lcur[dd >> LOG_SBS], 1);
            packed1[pos] = (unsigned)s.z | ((dd & (SBS - 1)) << 22);
        }
        {
            unsigned dd = (unsigned)d.w;
            int pos = atomicAdd(&lcur[dd >> LOG_SBS], 1);
            packed1[pos] = (unsigned)s.w | ((dd & (SBS - 1)) << 22);
        }
    }
    for (int e = e0 + n4 * 4 + t; e < e1; e += 256) {
        unsigned dd = (unsigned)dst0[e];
        int pos = atomicAdd(&lcur[dd >> LOG_SBS], 1);
        packed1[pos] = (unsigned)src0[e] | ((dd & (SBS - 1)) << 22);
    }
}

// ---- pass 2a: per-SB histogram + scan -> rp (ALL nodes of SB), dinv ----
__global__ __launch_bounds__(1024) void k_hist(
    const unsigned* __restrict__ packed1, const int* __restrict__ tot,
    int* __restrict__ rp, float* __restrict__ dinv, int N, int NSB, int CAP) {
    __shared__ int cnt[SBS];
    __shared__ int s2[SBS];
    __shared__ int sbase[NSB_MAX];
    int b = blockIdx.x, t = threadIdx.x;
    if (t < NSB_MAX) sbase[t] = (t < NSB) ? tot[t] : 0;
    cnt[t] = 0;
    __syncthreads();
    if (t == 0) {
        int run = 0;
        #pragma unroll 4
        for (int i = 0; i < NSB_MAX; ++i) { int c = sbase[i]; sbase[i] = run; run += c; }
    }
    __syncthreads();
    int cntb = tot[b];
    int e0 = b * CAP, e1 = e0 + cntb;
    int obase = sbase[b];
    int n4 = cntb >> 2;
    const ix4* p4 = (const ix4*)(packed1 + e0);
    for (int i = t; i < n4; i += 1024) {
        ix4 p = p4[i];
        atomicAdd(&cnt[((unsigned)p.x) >> 22], 1);
        atomicAdd(&cnt[((unsigned)p.y) >> 22], 1);
        atomicAdd(&cnt[((unsigned)p.z) >> 22], 1);
        atomicAdd(&cnt[((unsigned)p.w) >> 22], 1);
    }
    for (int e = e0 + n4 * 4 + t; e < e1; e += 1024)
        atomicAdd(&cnt[packed1[e] >> 22], 1);
    __syncthreads();
    int c = cnt[t];
    s2[t] = c;
    __syncthreads();
    for (int off = 1; off < 1024; off <<= 1) {
        int v = (t >= off) ? s2[t - off] : 0;
        __syncthreads();
        s2[t] += v;
        __syncthreads();
    }
    int ep = s2[t] - c;                 // exclusive prefix within SB
    int node = (b << LOG_SBS) + t;
    rp[node] = obase + ep;              // defined for ALL SB nodes
    if (node < N) dinv[node] = rsqrtf((float)(c + 1));   // +1 self-loop
}

// ---- pass 2b: placement, 8 slice-blocks per SB; LDS-staged sequential out ----
__global__ __launch_bounds__(512) void k_place(
    const unsigned* __restrict__ packed1, const int* __restrict__ tot,
    const int* __restrict__ rp, int* __restrict__ packed2,
    int NSB, int PADB, int CAP) {
    __shared__ int cur[SLICE];
    __shared__ int lbuf[PCAP];
    int bid = blockIdx.x;
    int s = bid / PADB, b = bid - s * PADB;
    if (b >= NSB) return;
    int t = threadIdx.x;
    int node0 = (b << LOG_SBS) + s * SLICE;
    int g0 = rp[node0];
    if (t < SLICE) cur[t] = rp[node0 + t] - g0;
    int slice_len = rp[node0 + SLICE] - g0;
    __syncthreads();
    int cntb = tot[b];
    int e0 = b * CAP, e1 = e0 + cntb;
    int n4 = cntb >> 2;
    const ix4* p4 = (const ix4*)(packed1 + e0);
    for (int i = t; i < n4; i += 512) {
        ix4 p = p4[i];
        {
            unsigned nd = ((unsigned)p.x) >> 22;
            if ((nd >> 7) == (unsigned)s) {
                int pos = atomicAdd(&cur[nd & (SLICE - 1)], 1);
                if (pos < PCAP) lbuf[pos] = p.x & SRC_MASK;
            }
        }
        {
            unsigned nd = ((unsigned)p.y) >> 22;
            if ((nd >> 7) == (unsigned)s) {
                int pos = atomicAdd(&cur[nd & (SLICE - 1)], 1);
                if (pos < PCAP) lbuf[pos] = p.y & SRC_MASK;
            }
        }
        {
            unsigned nd = ((unsigned)p.z) >> 22;
            if ((nd >> 7) == (unsigned)s) {
                int pos = atomicAdd(&cur[nd & (SLICE - 1)], 1);
                if (pos < PCAP) lbuf[pos] = p.z & SRC_MASK;
            }
        }
        {
            unsigned nd = ((unsigned)p.w) >> 22;
            if ((nd >> 7) == (unsigned)s) {
                int pos = atomicAdd(&cur[nd & (SLICE - 1)], 1);
                if (pos < PCAP) lbuf[pos] = p.w & SRC_MASK;
            }
        }
    }
    for (int e = e0 + n4 * 4 + t; e < e1; e += 512) {
        unsigned p = packed1[e];
        unsigned nd = p >> 22;
        if ((nd >> 7) == (unsigned)s) {
            int pos = atomicAdd(&cur[nd & (SLICE - 1)], 1);
            if (pos < PCAP) lbuf[pos] = (int)(p & SRC_MASK);
        }
    }
    __syncthreads();
    int lim = min(slice_len, PCAP);
    for (int i = t; i < lim; i += 512)
        packed2[g0 + i] = lbuf[i];      // sequential full-line writes
}

// ---- layer 1 GEMM: h1b = bf16((x@W1)*dinv) ----
__global__ __launch_bounds__(256) void k_gemm1(
    const float* __restrict__ x, const float* __restrict__ W1,
    const float* __restrict__ dinv, __hip_bfloat16* __restrict__ h1b, int N) {
    __shared__ float w[F_IN * H1];    // 8 KB
    __shared__ float xt[16 * F_IN];   // 8 KB
    int tid = threadIdx.x;
    int node0 = blockIdx.x * 16;

    const float4* W14 = (const float4*)W1;
    float4* w4 = (float4*)w;
    for (int i = tid; i < F_IN * H1 / 4; i += 256) w4[i] = W14[i];

    const float4* x4 = (const float4*)x;
    float4* xt4 = (float4*)xt;
    for (int i = tid; i < 16 * F_IN / 4; i += 256) {
        int r = i >> 5;
        int node = node0 + r;
        xt4[i] = (node < N) ? x4[(size_t)node * 32 + (i & 31)]
                            : make_float4(0.f, 0.f, 0.f, 0.f);
    }
    __syncthreads();

    int nsub = tid >> 4, f = tid & 15;
    int node = node0 + nsub;
    if (node < N) {
        const float* xr = xt + nsub * F_IN;
        float acc = 0.0f;
        #pragma unroll 16
        for (int k = 0; k < F_IN; ++k)
            acc = fmaf(xr[k], w[k * H1 + f], acc);
        h1b[(size_t)node * H1 + f] = __float2bfloat16(acc * dinv[node]);
    }
}

// ---- layer 1 aggregate + layer 2 transform, 4 threads per node (8B each) ----
__global__ __launch_bounds__(256) void k_agg1(
    const int* __restrict__ packed2, const int* __restrict__ rp,
    const __hip_bfloat16* __restrict__ h1b, const float* __restrict__ dinv,
    const float* __restrict__ b1, const float* __restrict__ W2,
    float* __restrict__ h2s, int N) {
    int tid = blockIdx.x * 256 + threadIdx.x;
    int n = tid >> 2, q = tid & 3;
    if (n >= N) return;
    const uint2* hv = (const uint2*)h1b;   // 8B chunks; row = 4 chunks
    float a[4];
    {   // self-loop init: own pre-scaled row quarter
        uint2 s = hv[(size_t)n * 4 + q];
        a[0] = bflo(s.x); a[1] = bfhi(s.x); a[2] = bflo(s.y); a[3] = bfhi(s.y);
    }
    int e = rp[n], e1 = rp[n + 1];
    for (; e + 8 <= e1; e += 8) {
        int p[8];
        #pragma unroll
        for (int u = 0; u < 8; ++u) p[u] = packed2[e + u];
        uint2 v[8];
        #pragma unroll
        for (int u = 0; u < 8; ++u) v[u] = hv[(size_t)p[u] * 4 + q];
        #pragma unroll
        for (int u = 0; u < 8; ++u) {
            a[0] += bflo(v[u].x); a[1] += bfhi(v[u].x);
            a[2] += bflo(v[u].y); a[3] += bfhi(v[u].y);
        }
    }
    for (; e < e1; ++e) {
        uint2 v = hv[(size_t)packed2[e] * 4 + q];
        a[0] += bflo(v.x); a[1] += bfhi(v.x); a[2] += bflo(v.y); a[3] += bfhi(v.y);
    }
    float dv = dinv[n];
    float c0 = 0.f, c1 = 0.f;
    #pragma unroll
    for (int j = 0; j < 4; ++j) {
        int f = q * 4 + j;
        float vv = fmaxf(fmaf(a[j], dv, b1[f]), 0.f);
        c0 = fmaf(vv, W2[f * C_OUT + 0], c0);
        c1 = fmaf(vv, W2[f * C_OUT + 1], c1);
    }
    c0 += __shfl_xor(c0, 1);
    c1 += __shfl_xor(c1, 1);
    c0 += __shfl_xor(c0, 2);
    c1 += __shfl_xor(c1, 2);
    if (q == 0)
        ((float2*)h2s)[n] = make_float2(c0 * dv, c1 * dv);
}

// ---- layer 2 aggregate + log_softmax, 2 threads per node (one channel each) ----
__global__ __launch_bounds__(256) void k_agg2(
    const int* __restrict__ packed2, const int* __restrict__ rp,
    const float* __restrict__ h2s, const float* __restrict__ dinv,
    const float* __restrict__ b2, float* __restrict__ out, int N) {
    int tid = blockIdx.x * 256 + threadIdx.x;
    int n = tid >> 1, q = tid & 1;
    if (n >= N) return;
    float a = h2s[2 * (size_t)n + q];   // self-loop
    int e = rp[n], e1 = rp[n + 1];
    for (; e + 8 <= e1; e += 8) {
        int p[8];
        #pragma unroll
        for (int u = 0; u < 8; ++u) p[u] = packed2[e + u];
        float v[8];
        #pragma unroll
        for (int u = 0; u < 8; ++u) v[u] = h2s[2 * (size_t)p[u] + q];
        #pragma unroll
        for (int u = 0; u < 8; ++u) a += v[u];
    }
    for (; e < e1; ++e) a += h2s[2 * (size_t)packed2[e] + q];
    float dv = dinv[n];
    a = fmaf(a, dv, b2[q]);
    float other = __shfl_xor(a, 1);
    if (q == 0) {
        float a0 = a, a1 = other;
        float m = fmaxf(a0, a1);
        float lse = m + logf(expf(a0 - m) + expf(a1 - m));
        ((float2*)out)[n] = make_float2(a0 - lse, a1 - lse);
    }
}

extern "C" void kernel_launch(void* const* d_in, const int* in_sizes, int n_in,
                              void* d_out, int out_size, void* d_ws, size_t ws_size,
                              hipStream_t stream) {
    const float* x  = (const float*)d_in[0];
    const int* ei   = (const int*)d_in[1];
    const float* W1 = (const float*)d_in[2];
    const float* b1 = (const float*)d_in[3];
    const float* W2 = (const float*)d_in[4];
    const float* b2 = (const float*)d_in[5];
    float* out = (float*)d_out;

    const int N = in_sizes[0] / F_IN;     // 100000 (assumed <= 131072)
    const int E = in_sizes[1] / 2;        // 3200000
    const int* src0 = ei;
    const int* dst0 = ei + E;

    const int NSB = (N + SBS - 1) >> LOG_SBS;    // 98
    const int nblk = (E + CH1 - 1) / CH1;        // 782 (must be <= 1024 for cscan)
    const int PADB = (NSB + 7) & ~7;             // 104 (x8 XCD-stable mapping)
    // per-SB capacity: expected (for a full SB) + 12.5% + 2048, 16-aligned
    int expSB = (int)(((long long)E << LOG_SBS) / N);
    int CAP = (expSB + expSB / 8 + 2048 + 15) & ~15;

    // workspace layout (float units), 16B-aligned chunks
    size_t off = 0;
    float* wsf = (float*)d_ws;
    auto take = [&](size_t nf) { float* p = wsf + off; off += (nf + 3) & ~(size_t)3; return p; };
    float* dinv    = take(N);
    __hip_bfloat16* h1b = (__hip_bfloat16*)take((size_t)N * H1 / 2);
    float* h2s     = take((size_t)N * C_OUT);
    unsigned* packed1 = (unsigned*)take((size_t)NSB * CAP);
    int*   packed2 = (int*)take(E);
    int*   cntm    = (int*)take((size_t)NSB * nblk);
    int*   tot     = (int*)take(NSB_MAX);
    int*   rp      = (int*)take((size_t)NSB * SBS + 1);

    k_cnt<<<nblk, 256, 0, stream>>>(dst0, cntm, E, NSB, nblk);
    k_cscan<<<NSB, 1024, 0, stream>>>(cntm, tot, rp, NSB, nblk, E);
    k_scat1<<<nblk, 256, 0, stream>>>(src0, dst0, cntm, packed1, E, NSB, nblk, CAP);
    k_hist<<<NSB, 1024, 0, stream>>>(packed1, tot, rp, dinv, N, NSB, CAP);
    k_place<<<NSLICE * PADB, 512, 0, stream>>>(packed1, tot, rp, packed2, NSB, PADB, CAP);
    k_gemm1<<<(N + 15) / 16, 256, 0, stream>>>(x, W1, dinv, h1b, N);
    k_agg1<<<(4 * N + 255) / 256, 256, 0, stream>>>(packed2, rp, h1b, dinv, b1, W2, h2s, N);
    k_agg2<<<(2 * N + 255) / 256, 256, 0, stream>>>(packed2, rp, h2s, dinv, b2, out, N);
}

// Round 16
// 128.061 us; speedup vs baseline: 1.2904x; 1.1012x over previous
//
#include <hip/hip_runtime.h>
#include <hip/hip_bf16.h>
#include <math.h>

// GCN 2-layer forward, round-16: r14/r15 pipeline with 3 fusions (8->6 launches):
//   k_cnt_gemm1: cnt and (unscaled) layer-1 GEMM in one kernel, disjoint block
//                ranges -> cnt + a launch gap hide under the 51MB x-read.
//   k_hist:      + epilogue scaling h1b *= dinv[node] in place (3.2MB, ~1us).
//   k_place_agg1: after staging the slice's node-sorted edges in lbuf, the same
//                block aggregates from LDS indices (register accumulation,
//                4 thr/node) -> deletes agg1's 13MB packed2 read + a launch.
//                packed2 still written for agg2.
// Assumes N <= 131072.

#define F_IN 128
#define H1 16
#define C_OUT 2
#define SBS 1024         // nodes per super-bucket
#define LOG_SBS 10
#define NSB_MAX 128
#define SRC_MASK 0x3FFFFF   // 22-bit src
#define CH1 4096         // edges per chunk (782 chunks)
#define SLICE 128        // nodes per place-slice
#define NSLICE (SBS / SLICE)   // 8
#define PCAP 5632        // staged edges per slice (expected ~4096, +24 sigma)

typedef int ix4 __attribute__((ext_vector_type(4)));

__device__ __forceinline__ float bflo(unsigned u) { return __uint_as_float(u << 16); }
__device__ __forceinline__ float bfhi(unsigned u) { return __uint_as_float(u & 0xFFFF0000u); }

// ---- fused: [0, nblk) = per-chunk SB histogram; [nblk, ..) = layer-1 GEMM ----
__global__ __launch_bounds__(256) void k_cnt_gemm1(
    const int* __restrict__ dst0, int* __restrict__ cntm,
    const float* __restrict__ x, const float* __restrict__ W1,
    __hip_bfloat16* __restrict__ h1b,
    int E, int NSB, int nblk, int N) {
    __shared__ int sc[NSB_MAX];
    __shared__ float w[F_IN * H1];    // 8 KB
    __shared__ float xt[16 * F_IN];   // 8 KB
    int t = threadIdx.x;
    if (blockIdx.x < (unsigned)nblk) {
        // ---- cnt ----
        if (t < NSB_MAX) sc[t] = 0;
        __syncthreads();
        int e0 = blockIdx.x * CH1, e1 = min(e0 + CH1, E);
        int n4 = (e1 - e0) >> 2;
        const ix4* d4 = (const ix4*)(dst0 + e0);
        for (int i = t; i < n4; i += 256) {
            ix4 d = __builtin_nontemporal_load(&d4[i]);
            atomicAdd(&sc[((unsigned)d.x) >> LOG_SBS], 1);
            atomicAdd(&sc[((unsigned)d.y) >> LOG_SBS], 1);
            atomicAdd(&sc[((unsigned)d.z) >> LOG_SBS], 1);
            atomicAdd(&sc[((unsigned)d.w) >> LOG_SBS], 1);
        }
        for (int e = e0 + n4 * 4 + t; e < e1; e += 256)
            atomicAdd(&sc[((unsigned)dst0[e]) >> LOG_SBS], 1);
        __syncthreads();
        for (int b = t; b < NSB; b += 256)
            cntm[(size_t)b * nblk + blockIdx.x] = sc[b];
    } else {
        // ---- gemm1 (UNSCALED h1) ----
        int node0 = (blockIdx.x - nblk) * 16;
        const float4* W14 = (const float4*)W1;
        float4* w4 = (float4*)w;
        for (int i = t; i < F_IN * H1 / 4; i += 256) w4[i] = W14[i];
        const float4* x4 = (const float4*)x;
        float4* xt4 = (float4*)xt;
        for (int i = t; i < 16 * F_IN / 4; i += 256) {
            int r = i >> 5;
            int node = node0 + r;
            xt4[i] = (node < N) ? x4[(size_t)node * 32 + (i & 31)]
                                : make_float4(0.f, 0.f, 0.f, 0.f);
        }
        __syncthreads();
        int nsub = t >> 4, f = t & 15;
        int node = node0 + nsub;
        if (node < N) {
            const float* xr = xt + nsub * F_IN;
            float acc = 0.0f;
            #pragma unroll 16
            for (int k = 0; k < F_IN; ++k)
                acc = fmaf(xr[k], w[k * H1 + f], acc);
            h1b[(size_t)node * H1 + f] = __float2bfloat16(acc);
        }
    }
}

// ---- pass 0b: per-SB exclusive scan over chunks (block per SB) + totals ----
__global__ __launch_bounds__(1024) void k_cscan(
    int* __restrict__ cntm, int* __restrict__ tot, int* __restrict__ rp,
    int NSB, int nblk, int E) {
    __shared__ int s[1024];
    int b = blockIdx.x, t = threadIdx.x;
    int* row = cntm + (size_t)b * nblk;
    int own = (t < nblk) ? row[t] : 0;
    s[t] = own;
    __syncthreads();
    for (int off = 1; off < 1024; off <<= 1) {
        int v = (t >= off) ? s[t - off] : 0;
        __syncthreads();
        s[t] += v;
        __syncthreads();
    }
    if (t < nblk) row[t] = s[t] - own;      // exclusive prefix
    if (t == 0) tot[b] = s[1023];           // SB total (zero-padded tail)
    if (b == 0 && t == 0) rp[NSB * SBS] = E;
}

// ---- pass 1: scatter (src | dst_local<<22) at precomputed offsets ----
__global__ __launch_bounds__(256) void k_scat1(
    const int* __restrict__ src0, const int* __restrict__ dst0,
    const int* __restrict__ cntm, unsigned* __restrict__ packed1,
    int E, int NSB, int nblk, int CAP) {
    __shared__ int lcur[NSB_MAX];
    int t = threadIdx.x, blk = blockIdx.x;
    for (int b = t; b < NSB; b += 256)
        lcur[b] = b * CAP + cntm[(size_t)b * nblk + blk];
    __syncthreads();
    int e0 = blk * CH1, e1 = min(e0 + CH1, E);
    int n4 = (e1 - e0) >> 2;
    const ix4* d4 = (const ix4*)(dst0 + e0);
    const ix4* s4 = (const ix4*)(src0 + e0);
    for (int i = t; i < n4; i += 256) {
        ix4 d = __builtin_nontemporal_load(&d4[i]);
        ix4 s = __builtin_nontemporal_load(&s4[i]);
        {
            unsigned dd = (unsigned)d.x;
            int pos = atomicAdd(&lcur[dd >> LOG_SBS], 1);
            packed1[pos] = (unsigned)s.x | ((dd & (SBS - 1)) << 22);
        }
        {
            unsigned dd = (unsigned)d.y;
            int pos = atomicAdd(&lcur[dd >> LOG_SBS], 1);
            packed1[pos] = (unsigned)s.y | ((dd & (SBS - 1)) << 22);
        }
        {
            unsigned dd = (unsigned)d.z;
            int pos = atomicAdd(&lcur[dd >> LOG_SBS], 1);
            packed1[pos] = (unsigned)s.z | ((dd & (SBS - 1)) << 22);
        }
        {
            unsigned dd = (unsigned)d.w;
            int pos = atomicAdd(&lcur[dd >> LOG_SBS], 1);
            packed1[pos] = (unsigned)s.w | ((dd & (SBS - 1)) << 22);
        }
    }
    for (int e = e0 + n4 * 4 + t; e < e1; e += 256) {
        unsigned dd = (unsigned)dst0[e];
        int pos = atomicAdd(&lcur[dd >> LOG_SBS], 1);
        packed1[pos] = (unsigned)src0[e] | ((dd & (SBS - 1)) << 22);
    }
}

// ---- pass 2a: per-SB histogram + scan -> rp, dinv; epilogue: h1b *= dinv ----
__global__ __launch_bounds__(1024) void k_hist(
    const unsigned* __restrict__ packed1, const int* __restrict__ tot,
    int* __restrict__ rp, float* __restrict__ dinv,
    __hip_bfloat16* __restrict__ h1b, int N, int NSB, int CAP) {
    __shared__ int cnt[SBS];
    __shared__ int s2[SBS];
    __shared__ int sbase[NSB_MAX];
    int b = blockIdx.x, t = threadIdx.x;
    if (t < NSB_MAX) sbase[t] = (t < NSB) ? tot[t] : 0;
    cnt[t] = 0;
    __syncthreads();
    if (t == 0) {
        int run = 0;
        #pragma unroll 4
        for (int i = 0; i < NSB_MAX; ++i) { int c = sbase[i]; sbase[i] = run; run += c; }
    }
    __syncthreads();
    int cntb = tot[b];
    int e0 = b * CAP, e1 = e0 + cntb;
    int obase = sbase[b];
    int n4 = cntb >> 2;
    const ix4* p4 = (const ix4*)(packed1 + e0);
    for (int i = t; i < n4; i += 1024) {
        ix4 p = p4[i];
        atomicAdd(&cnt[((unsigned)p.x) >> 22], 1);
        atomicAdd(&cnt[((unsigned)p.y) >> 22], 1);
        atomicAdd(&cnt[((unsigned)p.z) >> 22], 1);
        atomicAdd(&cnt[((unsigned)p.w) >> 22], 1);
    }
    for (int e = e0 + n4 * 4 + t; e < e1; e += 1024)
        atomicAdd(&cnt[packed1[e] >> 22], 1);
    __syncthreads();
    int c = cnt[t];
    s2[t] = c;
    __syncthreads();
    for (int off = 1; off < 1024; off <<= 1) {
        int v = (t >= off) ? s2[t - off] : 0;
        __syncthreads();
        s2[t] += v;
        __syncthreads();
    }
    int ep = s2[t] - c;                 // exclusive prefix within SB
    int node = (b << LOG_SBS) + t;
    rp[node] = obase + ep;              // defined for ALL SB nodes
    if (node < N) {
        float dv = rsqrtf((float)(c + 1));   // +1 self-loop
        dinv[node] = dv;
        // scale own h1b row in place (pre-scale by dinv[src])
        uint4* hrow = (uint4*)(h1b + (size_t)node * H1);
        uint4 s0 = hrow[0], s1 = hrow[1];
        unsigned r0[8];
        float v0, v1;
        #define SCALE_PACK(word, outi) \
            v0 = bflo(word) * dv; v1 = bfhi(word) * dv; \
            r0[outi] = (unsigned)__bfloat16_as_ushort(__float2bfloat16(v0)) | \
                       ((unsigned)__bfloat16_as_ushort(__float2bfloat16(v1)) << 16);
        SCALE_PACK(s0.x, 0) SCALE_PACK(s0.y, 1) SCALE_PACK(s0.z, 2) SCALE_PACK(s0.w, 3)
        SCALE_PACK(s1.x, 4) SCALE_PACK(s1.y, 5) SCALE_PACK(s1.z, 6) SCALE_PACK(s1.w, 7)
        #undef SCALE_PACK
        hrow[0] = make_uint4(r0[0], r0[1], r0[2], r0[3]);
        hrow[1] = make_uint4(r0[4], r0[5], r0[6], r0[7]);
    }
}

// ---- pass 2b+agg1: placement + in-block layer-1 aggregation ----
__global__ __launch_bounds__(512) void k_place_agg1(
    const unsigned* __restrict__ packed1, const int* __restrict__ tot,
    const int* __restrict__ rp, int* __restrict__ packed2,
    const __hip_bfloat16* __restrict__ h1b, const float* __restrict__ dinv,
    const float* __restrict__ b1, const float* __restrict__ W2,
    float* __restrict__ h2s,
    int N, int NSB, int PADB, int CAP) {
    __shared__ int cur[SLICE];
    __shared__ int lbuf[PCAP];
    int bid = blockIdx.x;
    int s = bid / PADB, b = bid - s * PADB;
    if (b >= NSB) return;
    int t = threadIdx.x;
    int node0 = (b << LOG_SBS) + s * SLICE;
    int g0 = rp[node0];
    if (t < SLICE) cur[t] = rp[node0 + t] - g0;
    int slice_len = rp[node0 + SLICE] - g0;
    __syncthreads();
    int cntb = tot[b];
    int e0 = b * CAP, e1 = e0 + cntb;
    int n4 = cntb >> 2;
    const ix4* p4 = (const ix4*)(packed1 + e0);
    for (int i = t; i < n4; i += 512) {
        ix4 p = p4[i];
        {
            unsigned nd = ((unsigned)p.x) >> 22;
            if ((nd >> 7) == (unsigned)s) {
                int pos = atomicAdd(&cur[nd & (SLICE - 1)], 1);
                if (pos < PCAP) lbuf[pos] = p.x & SRC_MASK;
            }
        }
        {
            unsigned nd = ((unsigned)p.y) >> 22;
            if ((nd >> 7) == (unsigned)s) {
                int pos = atomicAdd(&cur[nd & (SLICE - 1)], 1);
                if (pos < PCAP) lbuf[pos] = p.y & SRC_MASK;
            }
        }
        {
            unsigned nd = ((unsigned)p.z) >> 22;
            if ((nd >> 7) == (unsigned)s) {
                int pos = atomicAdd(&cur[nd & (SLICE - 1)], 1);
                if (pos < PCAP) lbuf[pos] = p.z & SRC_MASK;
            }
        }
        {
            unsigned nd = ((unsigned)p.w) >> 22;
            if ((nd >> 7) == (unsigned)s) {
                int pos = atomicAdd(&cur[nd & (SLICE - 1)], 1);
                if (pos < PCAP) lbuf[pos] = p.w & SRC_MASK;
            }
        }
    }
    for (int e = e0 + n4 * 4 + t; e < e1; e += 512) {
        unsigned p = packed1[e];
        unsigned nd = p >> 22;
        if ((nd >> 7) == (unsigned)s) {
            int pos = atomicAdd(&cur[nd & (SLICE - 1)], 1);
            if (pos < PCAP) lbuf[pos] = (int)(p & SRC_MASK);
        }
    }
    __syncthreads();
    // write packed2 for agg2 (sequential full-line writes)
    int lim = min(slice_len, PCAP);
    for (int i = t; i < lim; i += 512)
        packed2[g0 + i] = lbuf[i];
    // ---- fused layer-1 aggregation: 4 threads/node from LDS indices ----
    int g = t >> 2, q = t & 3;          // g in [0,128)
    int node = node0 + g;
    if (node < N) {
        const uint2* hv = (const uint2*)h1b;   // 8B chunks; row = 4 chunks
        float a[4];
        uint2 sv = hv[(size_t)node * 4 + q];   // self (pre-scaled)
        a[0] = bflo(sv.x); a[1] = bfhi(sv.x); a[2] = bflo(sv.y); a[3] = bfhi(sv.y);
        int lb = rp[node] - g0;
        int le = min(rp[node + 1] - g0, PCAP);
        for (; lb + 8 <= le; lb += 8) {
            int p[8];
            #pragma unroll
            for (int u = 0; u < 8; ++u) p[u] = lbuf[lb + u];
            uint2 v[8];
            #pragma unroll
            for (int u = 0; u < 8; ++u) v[u] = hv[(size_t)p[u] * 4 + q];
            #pragma unroll
            for (int u = 0; u < 8; ++u) {
                a[0] += bflo(v[u].x); a[1] += bfhi(v[u].x);
                a[2] += bflo(v[u].y); a[3] += bfhi(v[u].y);
            }
        }
        for (; lb < le; ++lb) {
            uint2 v = hv[(size_t)lbuf[lb] * 4 + q];
            a[0] += bflo(v.x); a[1] += bfhi(v.x); a[2] += bflo(v.y); a[3] += bfhi(v.y);
        }
        float dv = dinv[node];
        float c0 = 0.f, c1 = 0.f;
        #pragma unroll
        for (int j = 0; j < 4; ++j) {
            int f = q * 4 + j;
            float vv = fmaxf(fmaf(a[j], dv, b1[f]), 0.f);
            c0 = fmaf(vv, W2[f * C_OUT + 0], c0);
            c1 = fmaf(vv, W2[f * C_OUT + 1], c1);
        }
        c0 += __shfl_xor(c0, 1);
        c1 += __shfl_xor(c1, 1);
        c0 += __shfl_xor(c0, 2);
        c1 += __shfl_xor(c1, 2);
        if (q == 0)
            ((float2*)h2s)[node] = make_float2(c0 * dv, c1 * dv);
    }
}

// ---- layer 2 aggregate + log_softmax, 2 threads per node ----
__global__ __launch_bounds__(256) void k_agg2(
    const int* __restrict__ packed2, const int* __restrict__ rp,
    const float* __restrict__ h2s, const float* __restrict__ dinv,
    const float* __restrict__ b2, float* __restrict__ out, int N) {
    int tid = blockIdx.x * 256 + threadIdx.x;
    int n = tid >> 1, q = tid & 1;
    if (n >= N) return;
    float a = h2s[2 * (size_t)n + q];   // self-loop
    int e = rp[n], e1 = rp[n + 1];
    for (; e + 8 <= e1; e += 8) {
        int p[8];
        #pragma unroll
        for (int u = 0; u < 8; ++u) p[u] = packed2[e + u];
        float v[8];
        #pragma unroll
        for (int u = 0; u < 8; ++u) v[u] = h2s[2 * (size_t)p[u] + q];
        #pragma unroll
        for (int u = 0; u < 8; ++u) a += v[u];
    }
    for (; e < e1; ++e) a += h2s[2 * (size_t)packed2[e] + q];
    float dv = dinv[n];
    a = fmaf(a, dv, b2[q]);
    float other = __shfl_xor(a, 1);
    if (q == 0) {
        float a0 = a, a1 = other;
        float m = fmaxf(a0, a1);
        float lse = m + logf(expf(a0 - m) + expf(a1 - m));
        ((float2*)out)[n] = make_float2(a0 - lse, a1 - lse);
    }
}

extern "C" void kernel_launch(void* const* d_in, const int* in_sizes, int n_in,
                              void* d_out, int out_size, void* d_ws, size_t ws_size,
                              hipStream_t stream) {
    const float* x  = (const float*)d_in[0];
    const int* ei   = (const int*)d_in[1];
    const float* W1 = (const float*)d_in[2];
    const float* b1 = (const float*)d_in[3];
    const float* W2 = (const float*)d_in[4];
    const float* b2 = (const float*)d_in[5];
    float* out = (float*)d_out;

    const int N = in_sizes[0] / F_IN;     // 100000 (assumed <= 131072)
    const int E = in_sizes[1] / 2;        // 3200000
    const int* src0 = ei;
    const int* dst0 = ei + E;

    const int NSB = (N + SBS - 1) >> LOG_SBS;    // 98
    const int nblk = (E + CH1 - 1) / CH1;        // 782 (must be <= 1024 for cscan)
    const int PADB = (NSB + 7) & ~7;             // 104 (x8 XCD-stable mapping)
    // per-SB capacity: expected (for a full SB) + 12.5% + 2048, 16-aligned
    int expSB = (int)(((long long)E << LOG_SBS) / N);
    int CAP = (expSB + expSB / 8 + 2048 + 15) & ~15;

    // workspace layout (float units), 16B-aligned chunks
    size_t off = 0;
    float* wsf = (float*)d_ws;
    auto take = [&](size_t nf) { float* p = wsf + off; off += (nf + 3) & ~(size_t)3; return p; };
    float* dinv    = take(N);
    __hip_bfloat16* h1b = (__hip_bfloat16*)take((size_t)N * H1 / 2);
    float* h2s     = take((size_t)N * C_OUT);
    unsigned* packed1 = (unsigned*)take((size_t)NSB * CAP);
    int*   packed2 = (int*)take(E);
    int*   cntm    = (int*)take((size_t)NSB * nblk);
    int*   tot     = (int*)take(NSB_MAX);
    int*   rp      = (int*)take((size_t)NSB * SBS + 1);

    int nbGemm = (N + 15) / 16;
    k_cnt_gemm1<<<nblk + nbGemm, 256, 0, stream>>>(dst0, cntm, x, W1, h1b, E, NSB, nblk, N);
    k_cscan<<<NSB, 1024, 0, stream>>>(cntm, tot, rp, NSB, nblk, E);
    k_scat1<<<nblk, 256, 0, stream>>>(src0, dst0, cntm, packed1, E, NSB, nblk, CAP);
    k_hist<<<NSB, 1024, 0, stream>>>(packed1, tot, rp, dinv, h1b, N, NSB, CAP);
    k_place_agg1<<<NSLICE * PADB, 512, 0, stream>>>(packed1, tot, rp, packed2,
                                                    h1b, dinv, b1, W2, h2s, N, NSB, PADB, CAP);
    k_agg2<<<(2 * N + 255) / 256, 256, 0, stream>>>(packed2, rp, h2s, dinv, b2, out, N);
}